// Round 1
// baseline (1499.462 us; speedup 1.0000x reference)
//
#include <hip/hip_runtime.h>
#include <stdint.h>

#define NITEMS 50000
#define SEQ    200
#define TMAX   199

// ws layout:
//   [0,     8192): flags, 64 groups * 32 ints (padded to 128B/group)
//   [8192,  8200): accum {nll_sum, cnt}
//   [12288, 12288 + 64*2*256*4): h exchange buffer (group, parity, 256)

template<int CTRL>
__device__ __forceinline__ float dpp_add(float x) {
    int r = __builtin_amdgcn_update_dpp(0, __float_as_int(x), CTRL, 0xF, 0xF, true);
    return x + __int_as_float(r);
}

__global__ __launch_bounds__(512, 2)
void lstm_main(const int* __restrict__ items, const int* __restrict__ actions,
               const float* __restrict__ WihT, const float* __restrict__ Whh,
               const float* __restrict__ b_lstm, const float* __restrict__ trans_emb,
               const float* __restrict__ Wq, const float* __restrict__ bq,
               int* flags, float* h_buf, float* accum)
{
    const int bid  = blockIdx.x;
    // XCD-locality heuristic: group's 4 blocks share bid%8 (same XCD under round-robin).
    const int g    = (bid & 7) + 8 * ((bid >> 3) >> 2);   // batch/group 0..63
    const int q    = (bid >> 3) & 3;                      // quarter 0..3
    const int tid  = threadIdx.x;
    const int lane = tid & 63;
    const int wv   = tid >> 6;
    const int rg   = tid >> 4;    // 0..31 rowgroup (8 rows each)
    const int kc   = tid & 15;    // 0..15 k-chunk (16 k each)

    __shared__ float xp_lds[2][256];
    __shared__ float gate_lds[256];
    __shared__ float b_lds[256];
    __shared__ float emb_lds[2][256];
    __shared__ float wq_lds[2][256];
    __shared__ float bq_lds[2];
    __shared__ int   items_s[SEQ];
    __shared__ int   act_s[SEQ];
    __shared__ int   len_sh;

    // ---------------- prologue ----------------
    for (int i = tid; i < SEQ; i += 512) {
        items_s[i] = items[g * SEQ + i];
        act_s[i]   = actions[g * SEQ + i];
    }
    if (tid < 256) {
        b_lds[tid] = b_lstm[(tid >> 6) * 256 + q * 64 + (tid & 63)];
    } else {
        const int k = tid - 256;
        wq_lds[0][k] = Wq[k];
        wq_lds[1][k] = Wq[256 + k];
    }
    if (tid == 0) { bq_lds[0] = bq[0]; bq_lds[1] = bq[1]; }
    __syncthreads();
    if (tid == 0) {
        int L = 0;
        while (L < SEQ && items_s[L] != 0) ++L;   // valid region is a prefix
        len_sh = L;
    }
    __syncthreads();
    const int len = len_sh;           // 100..200
    const int L   = min(len, TMAX);   // LSTM steps

    // Whh slice into registers: thread (rg,kc) holds rows rg*8..+8, k in [16*kc,16*kc+16)
    float wgt[8][16];
    #pragma unroll
    for (int r = 0; r < 8; ++r) {
        const int r_blk = rg * 8 + r;                               // 0..255
        const int j = (r_blk >> 6) * 256 + q * 64 + (r_blk & 63);   // global gate row
        const float4* wp = (const float4*)(Whh + (size_t)j * 256 + kc * 16);
        #pragma unroll
        for (int m = 0; m < 4; ++m) {
            float4 v = wp[m];
            wgt[r][4*m+0] = v.x; wgt[r][4*m+1] = v.y;
            wgt[r][4*m+2] = v.z; wgt[r][4*m+3] = v.w;
        }
    }

    // stage x_proj for t=0
    if (wv == 0) {
        const int it = items_s[0], ac = act_s[0];
        const int c = lane >> 4, off = (lane & 15) * 4;
        float4 va = *(const float4*)(WihT + (size_t)it * 1024 + c * 256 + q * 64 + off);
        float4 vb = *(const float4*)(WihT + (size_t)(NITEMS + ac) * 1024 + c * 256 + q * 64 + off);
        *(float4*)&xp_lds[0][c * 64 + off] =
            make_float4(va.x+vb.x, va.y+vb.y, va.z+vb.z, va.w+vb.w);
    }
    // stage emb for token 0 (q_it = items[1])
    if (q == 0 && wv == 2) {
        const int qe = items_s[1];
        float4 e = make_float4(0.f,0.f,0.f,0.f);
        if (qe != 0) e = *(const float4*)(trans_emb + (size_t)qe * 256 + 4 * lane);
        *(float4*)&emb_lds[0][4 * lane] = e;
    }
    __syncthreads();

    float c_cell = 0.f;                 // used by tid<64 only
    float nll_acc = 0.f, cnt_acc = 0.f; // used by wave2/q0 lane0 only
    float hreg[16];
    #pragma unroll
    for (int m = 0; m < 16; ++m) hreg[m] = 0.f;

    int*   myflags = flags + g * 32;
    float* hb      = h_buf + (size_t)g * 512;   // [parity][256]

    for (int t = 0; t < L; ++t) {
        // ---- stage 1: obtain h^t ----
        if (t > 0) {
            if (tid < 4 && tid != q) {
                int guard = 0;
                while (__hip_atomic_load(&myflags[tid], __ATOMIC_ACQUIRE,
                                         __HIP_MEMORY_SCOPE_AGENT) < t) {
                    __builtin_amdgcn_s_sleep(1);
                    if (++guard > (1 << 16)) break;   // bounded: never hang
                }
            }
            __syncthreads();
            unsigned long long* hp = (unsigned long long*)(hb + (t & 1) * 256 + kc * 16);
            #pragma unroll
            for (int m = 0; m < 8; ++m) {
                unsigned long long u = __hip_atomic_load(&hp[m], __ATOMIC_RELAXED,
                                                         __HIP_MEMORY_SCOPE_AGENT);
                union { unsigned long long u; float f[2]; } cv; cv.u = u;
                hreg[2*m]   = cv.f[0];
                hreg[2*m+1] = cv.f[1];
            }
        }

        // ---- early issues (consumed after B1; hides HBM latency) ----
        const int tn = t + 1;
        float4 xa = make_float4(0,0,0,0), xb = make_float4(0,0,0,0);
        float4 ev = make_float4(0,0,0,0);
        float  he[4] = {0,0,0,0};
        if (wv == 1 && tn < L) {
            const int it = items_s[tn], ac = act_s[tn];
            const int c = lane >> 4, off = (lane & 15) * 4;
            xa = *(const float4*)(WihT + (size_t)it * 1024 + c * 256 + q * 64 + off);
            xb = *(const float4*)(WihT + (size_t)(NITEMS + ac) * 1024 + c * 256 + q * 64 + off);
        }
        if (q == 0 && wv == 2) {
            const int qe = items_s[tn];           // tn <= 199, in range
            if (qe != 0) ev = *(const float4*)(trans_emb + (size_t)qe * 256 + 4 * lane);
            if (t >= 1) {
                unsigned long long* hp2 = (unsigned long long*)(hb + (t & 1) * 256 + 4 * lane);
                unsigned long long u0 = __hip_atomic_load(&hp2[0], __ATOMIC_RELAXED,
                                                          __HIP_MEMORY_SCOPE_AGENT);
                unsigned long long u1 = __hip_atomic_load(&hp2[1], __ATOMIC_RELAXED,
                                                          __HIP_MEMORY_SCOPE_AGENT);
                union { unsigned long long u; float f[2]; } c0, c1; c0.u = u0; c1.u = u1;
                he[0] = c0.f[0]; he[1] = c0.f[1]; he[2] = c1.f[0]; he[3] = c1.f[1];
            }
        }

        // ---- stage 2: partial dot products (weights in regs) ----
        float acc[8];
        #pragma unroll
        for (int r = 0; r < 8; ++r) acc[r] = 0.f;
        #pragma unroll
        for (int m = 0; m < 16; ++m) {
            #pragma unroll
            for (int r = 0; r < 8; ++r) acc[r] = fmaf(wgt[r][m], hreg[m], acc[r]);
        }
        // ---- stage 3: 16-lane reduce over kc via DPP row rotations (VALU pipe) ----
        #pragma unroll
        for (int r = 0; r < 8; ++r) {
            float v = acc[r];
            v = dpp_add<0x128>(v);   // row_ror:8
            v = dpp_add<0x124>(v);   // row_ror:4
            v = dpp_add<0x122>(v);   // row_ror:2
            v = dpp_add<0x121>(v);   // row_ror:1
            acc[r] = v;
        }
        if (kc == 0) {
            #pragma unroll
            for (int r = 0; r < 8; ++r) {
                const int r_blk = rg * 8 + r;
                gate_lds[r_blk] = acc[r] + xp_lds[t & 1][r_blk] + b_lds[r_blk];
            }
        }
        __syncthreads();   // B1

        // ---- stage 4: per-wave roles ----
        if (tid < 64) {
            const int d = tid;
            float gi = gate_lds[d];
            float gf = gate_lds[64 + d];
            float gg = gate_lds[128 + d];
            float go = gate_lds[192 + d];
            float ii = 1.f / (1.f + __expf(-gi));
            float ff = 1.f / (1.f + __expf(-gf));
            float oo = 1.f / (1.f + __expf(-go));
            float gt = tanhf(gg);
            c_cell = ff * c_cell + ii * gt;
            float hn = oo * tanhf(c_cell);
            __hip_atomic_store(&hb[((t + 1) & 1) * 256 + q * 64 + d], hn,
                               __ATOMIC_RELAXED, __HIP_MEMORY_SCOPE_AGENT);
            if (d == 0)
                __hip_atomic_store(&myflags[q], t + 1,
                                   __ATOMIC_RELEASE, __HIP_MEMORY_SCOPE_AGENT);
        } else if (wv == 1) {
            if (tn < L) {
                const int c = lane >> 4, off = (lane & 15) * 4;
                *(float4*)&xp_lds[tn & 1][c * 64 + off] =
                    make_float4(xa.x+xb.x, xa.y+xb.y, xa.z+xb.z, xa.w+xb.w);
            }
        } else if (wv == 2 && q == 0) {
            if (t >= 1) {   // token t-1; always valid since t < L <= len
                const float* eb = &emb_lds[(t - 1) & 1][0];
                float s0 = 0.f, s1 = 0.f;
                #pragma unroll
                for (int m = 0; m < 4; ++m) {
                    const int k = 4 * lane + m;
                    float p = eb[k] * he[m];
                    s0 = fmaf(p, wq_lds[0][k], s0);
                    s1 = fmaf(p, wq_lds[1][k], s1);
                }
                #pragma unroll
                for (int off2 = 32; off2; off2 >>= 1) {
                    s0 += __shfl_xor(s0, off2);
                    s1 += __shfl_xor(s1, off2);
                }
                if (lane == 0) {
                    const int tgt = act_s[t];     // actions[b, (t-1)+1]
                    float z0 = s0 + bq_lds[0], z1 = s1 + bq_lds[1];
                    float mz = fmaxf(z0, z1);
                    float lse = mz + __logf(__expf(z0 - mz) + __expf(z1 - mz));
                    nll_acc += lse - (tgt ? z1 : z0);
                    cnt_acc += 1.f;
                }
            }
            *(float4*)&emb_lds[t & 1][4 * lane] = ev;   // stage emb for token t
        }
        __syncthreads();   // B2
    }

    // ---- final token (t = L-1 uses h^L); valid only when len==200 ----
    if (q == 0 && wv == 2) {
        if (items_s[L] != 0) {
            if (lane < 4) {
                int guard = 0;
                while (__hip_atomic_load(&myflags[lane], __ATOMIC_ACQUIRE,
                                         __HIP_MEMORY_SCOPE_AGENT) < L) {
                    __builtin_amdgcn_s_sleep(1);
                    if (++guard > (1 << 16)) break;
                }
            }
            // wave lockstep: lanes 4..63 reconverge after the masked spin
            unsigned long long* hp2 = (unsigned long long*)(hb + (L & 1) * 256 + 4 * lane);
            unsigned long long u0 = __hip_atomic_load(&hp2[0], __ATOMIC_RELAXED,
                                                      __HIP_MEMORY_SCOPE_AGENT);
            unsigned long long u1 = __hip_atomic_load(&hp2[1], __ATOMIC_RELAXED,
                                                      __HIP_MEMORY_SCOPE_AGENT);
            union { unsigned long long u; float f[2]; } c0, c1; c0.u = u0; c1.u = u1;
            float he2[4] = { c0.f[0], c0.f[1], c1.f[0], c1.f[1] };
            const float* eb = &emb_lds[(L - 1) & 1][0];
            float s0 = 0.f, s1 = 0.f;
            #pragma unroll
            for (int m = 0; m < 4; ++m) {
                const int k = 4 * lane + m;
                float p = eb[k] * he2[m];
                s0 = fmaf(p, wq_lds[0][k], s0);
                s1 = fmaf(p, wq_lds[1][k], s1);
            }
            #pragma unroll
            for (int off2 = 32; off2; off2 >>= 1) {
                s0 += __shfl_xor(s0, off2);
                s1 += __shfl_xor(s1, off2);
            }
            if (lane == 0) {
                const int tgt = act_s[L];
                float z0 = s0 + bq_lds[0], z1 = s1 + bq_lds[1];
                float mz = fmaxf(z0, z1);
                float lse = mz + __logf(__expf(z0 - mz) + __expf(z1 - mz));
                nll_acc += lse - (tgt ? z1 : z0);
                cnt_acc += 1.f;
            }
        }
        if (lane == 0) {
            atomicAdd(&accum[0], nll_acc);
            atomicAdd(&accum[1], cnt_acc);
        }
    }
}

__global__ void finalize_k(const float* __restrict__ accum, float* __restrict__ out) {
    out[0] = accum[0] / accum[1];
}

extern "C" void kernel_launch(void* const* d_in, const int* in_sizes, int n_in,
                              void* d_out, int out_size, void* d_ws, size_t ws_size,
                              hipStream_t stream)
{
    const int*   items     = (const int*)d_in[0];
    const int*   actions   = (const int*)d_in[1];
    const float* WihT      = (const float*)d_in[2];
    const float* Whh       = (const float*)d_in[3];
    const float* b_lstm    = (const float*)d_in[4];
    const float* trans_emb = (const float*)d_in[5];
    const float* Wq        = (const float*)d_in[6];
    const float* bq        = (const float*)d_in[7];

    char*  ws    = (char*)d_ws;
    int*   flags = (int*)ws;                   // 8192 B (64 groups * 128 B)
    float* accum = (float*)(ws + 8192);        // 8 B
    float* h_buf = (float*)(ws + 12288);       // 64*2*256*4 = 131072 B

    hipMemsetAsync(d_ws, 0, 12288 + 64 * 2 * 256 * 4, stream);

    lstm_main<<<dim3(256), dim3(512), 0, stream>>>(
        items, actions, WihT, Whh, b_lstm, trans_emb, Wq, bq, flags, h_buf, accum);
    finalize_k<<<dim3(1), dim3(1), 0, stream>>>(accum, (float*)d_out);
}